// Round 1
// baseline (134.297 us; speedup 1.0000x reference)
//
#include <hip/hip_runtime.h>

// GSCAN embed + nonzero-masked scatter, fused.
// situation: [B,H,W,17] f32 ; out: [B,H,W,64] f32
// out[cell, 0:16]  = s[0:4]  @ W_size   (if mask)
// out[cell,16:32]  = s[4:8]  @ W_shape
// out[cell,32:48]  = s[8:12] @ W_rgb
// out[cell,48:64]  = s[12:17]@ W_agent
// mask = sum(s[0:17]) > 0 ; else out = [s[0:17], zeros(47)]

#define TILE_CELLS 64          // cells per block-tile
#define TILE_F     (TILE_CELLS * 17)   // 1088 floats staged
#define TILE_F4    (TILE_F / 4)        // 272 float4

__global__ __launch_bounds__(256, 8) void gscan_embed_kernel(
    const float* __restrict__ sit,
    const float* __restrict__ W_size,
    const float* __restrict__ W_shape,
    const float* __restrict__ W_rgb,
    const float* __restrict__ W_agent,
    float* __restrict__ out,
    int ntiles)
{
    __shared__ float s[TILE_F + 8];   // +pad: fallback path may touch sc[17..19] of cell 63
    __shared__ float csum[TILE_CELLS];

    const int tid    = threadIdx.x;
    const int quad   = tid & 15;       // which float4 of the 16 per cell (fixed per thread)
    const int g      = quad >> 2;      // channel group 0..3
    const int c0     = (quad & 3) * 4; // column offset within the 16-wide group
    const int in_off = g * 4;          // first input channel of this group

    // Per-thread loop-invariant weight slice: 4 output cols x up to 5 rows.
    // Groups 0..2 get a zero 5th row (multiplies the always-valid s[16]).
    const float* Wg = (g == 0) ? W_size : (g == 1) ? W_shape : (g == 2) ? W_rgb : W_agent;
    const float4 w0 = *reinterpret_cast<const float4*>(Wg + 0 * 16 + c0);
    const float4 w1 = *reinterpret_cast<const float4*>(Wg + 1 * 16 + c0);
    const float4 w2 = *reinterpret_cast<const float4*>(Wg + 2 * 16 + c0);
    const float4 w3 = *reinterpret_cast<const float4*>(Wg + 3 * 16 + c0);
    const float4 w4 = (g == 3) ? *reinterpret_cast<const float4*>(Wg + 4 * 16 + c0)
                               : make_float4(0.f, 0.f, 0.f, 0.f);

    for (int tile = blockIdx.x; tile < ntiles; tile += gridDim.x) {
        __syncthreads();  // LDS reuse guard vs previous iteration's readers

        // Stage 64 cells x 17 channels, coalesced float4 loads.
        const float4* src = reinterpret_cast<const float4*>(sit) + (size_t)tile * TILE_F4;
        float4* dst = reinterpret_cast<float4*>(s);
        dst[tid] = src[tid];
        if (tid < TILE_F4 - 256) dst[256 + tid] = src[256 + tid];
        __syncthreads();

        // Per-cell channel sums (mask input).
        if (tid < TILE_CELLS) {
            const float* sc = s + tid * 17;
            float acc = 0.f;
            #pragma unroll
            for (int k = 0; k < 17; ++k) acc += sc[k];
            csum[tid] = acc;
        }
        __syncthreads();

        float4* outv = reinterpret_cast<float4*>(out) + (size_t)tile * (TILE_CELLS * 16);
        #pragma unroll
        for (int k = 0; k < 4; ++k) {
            const int f    = tid + k * 256;   // float4 index within tile (0..1023)
            const int cell = f >> 4;          // 0..63
            const float* sc = s + cell * 17;

            const float x0 = sc[in_off + 0];
            const float x1 = sc[in_off + 1];
            const float x2 = sc[in_off + 2];
            const float x3 = sc[in_off + 3];
            const float x4 = sc[16];          // 5th agent channel (w4==0 for g<3)

            float4 e;
            e.x = x0 * w0.x + x1 * w1.x + x2 * w2.x + x3 * w3.x + x4 * w4.x;
            e.y = x0 * w0.y + x1 * w1.y + x2 * w2.y + x3 * w3.y + x4 * w4.y;
            e.z = x0 * w0.z + x1 * w1.z + x2 * w2.z + x3 * w3.z + x4 * w4.z;
            e.w = x0 * w0.w + x1 * w1.w + x2 * w2.w + x3 * w3.w + x4 * w4.w;

            const bool m = csum[cell] > 0.f;
            const int  j = quad * 4;          // output channel of .x
            float4 r;
            r.x = m ? e.x : ((j + 0) < 17 ? sc[j + 0] : 0.f);
            r.y = m ? e.y : ((j + 1) < 17 ? sc[j + 1] : 0.f);
            r.z = m ? e.z : ((j + 2) < 17 ? sc[j + 2] : 0.f);
            r.w = m ? e.w : ((j + 3) < 17 ? sc[j + 3] : 0.f);

            outv[f] = r;   // contiguous: wave writes 4 KB per iteration
        }
    }
}

extern "C" void kernel_launch(void* const* d_in, const int* in_sizes, int n_in,
                              void* d_out, int out_size, void* d_ws, size_t ws_size,
                              hipStream_t stream) {
    const float* sit = (const float*)d_in[0];
    const float* Wsz = (const float*)d_in[1];
    const float* Wsh = (const float*)d_in[2];
    const float* Wrg = (const float*)d_in[3];
    const float* Wag = (const float*)d_in[4];
    float* out = (float*)d_out;

    const int ncells = in_sizes[0] / 17;          // 2048*32*32 = 2,097,152
    const int ntiles = ncells / TILE_CELLS;       // 32768 (exactly divisible)

    int grid = ntiles < 2048 ? ntiles : 2048;     // 8 blocks/CU x 256 CU, grid-stride
    gscan_embed_kernel<<<grid, 256, 0, stream>>>(sit, Wsz, Wsh, Wrg, Wag, out, ntiles);
}

// Round 3
// 96.758 us; speedup vs baseline: 1.3880x; 1.3880x over previous
//
#include <hip/hip_runtime.h>

// GSCAN embed + nonzero-masked scatter, fused.
// situation: [B,H,W,17] f32 ; out: [B,H,W,64] f32
// out[cell, 0:16]  = s[0:4]  @ W_size   (if mask)
// out[cell,16:32]  = s[4:8]  @ W_shape
// out[cell,32:48]  = s[8:12] @ W_rgb
// out[cell,48:64]  = s[12:17]@ W_agent
// mask = sum(s[0:17]) > 0 ; else out = [s[0:17], zeros(47)]
//
// R1: one tile per block (no grid-stride loop -> no per-iteration vmcnt(0)
//     store-drain barrier), nontemporal stores for the 537 MB write stream.
// R2: nontemporal store needs a NATIVE vector type (ext_vector_type), not
//     HIP's float4 class — same layout, just a type the builtin accepts.

#define TILE_CELLS 64                  // cells per block-tile
#define TILE_F     (TILE_CELLS * 17)   // 1088 floats staged
#define TILE_F4    (TILE_F / 4)        // 272 float4

typedef float f32x4 __attribute__((ext_vector_type(4)));

__global__ __launch_bounds__(256, 8) void gscan_embed_kernel(
    const float* __restrict__ sit,
    const float* __restrict__ W_size,
    const float* __restrict__ W_shape,
    const float* __restrict__ W_rgb,
    const float* __restrict__ W_agent,
    float* __restrict__ out)
{
    __shared__ float s[TILE_F + 8];   // +pad: fallback path may touch sc[17..19] of cell 63
    __shared__ float csum[TILE_CELLS];

    const int tid    = threadIdx.x;
    const int tile   = blockIdx.x;
    const int quad   = tid & 15;       // which float4 of the 16 per cell (fixed per thread)
    const int g      = quad >> 2;      // channel group 0..3
    const int c0     = (quad & 3) * 4; // column offset within the 16-wide group
    const int in_off = g * 4;          // first input channel of this group

    // Stage 64 cells x 17 channels, coalesced float4 loads (start ASAP).
    const f32x4* src = reinterpret_cast<const f32x4*>(sit) + (size_t)tile * TILE_F4;
    f32x4* dst = reinterpret_cast<f32x4*>(s);
    dst[tid] = src[tid];
    if (tid < TILE_F4 - 256) dst[256 + tid] = src[256 + tid];

    // Per-thread loop-invariant weight slice: 4 output cols x up to 5 rows.
    // Groups 0..2 get a zero 5th row (multiplies the always-valid s[16]).
    const float* Wg = (g == 0) ? W_size : (g == 1) ? W_shape : (g == 2) ? W_rgb : W_agent;
    const f32x4 w0 = *reinterpret_cast<const f32x4*>(Wg + 0 * 16 + c0);
    const f32x4 w1 = *reinterpret_cast<const f32x4*>(Wg + 1 * 16 + c0);
    const f32x4 w2 = *reinterpret_cast<const f32x4*>(Wg + 2 * 16 + c0);
    const f32x4 w3 = *reinterpret_cast<const f32x4*>(Wg + 3 * 16 + c0);
    const f32x4 w4 = (g == 3) ? *reinterpret_cast<const f32x4*>(Wg + 4 * 16 + c0)
                              : (f32x4)(0.f);

    __syncthreads();

    // Per-cell channel sums (mask input). Sequential order — matches the
    // verified-passing R0 rounding behavior.
    if (tid < TILE_CELLS) {
        const float* sc = s + tid * 17;
        float acc = 0.f;
        #pragma unroll
        for (int k = 0; k < 17; ++k) acc += sc[k];
        csum[tid] = acc;
    }
    __syncthreads();

    f32x4* outv = reinterpret_cast<f32x4*>(out) + (size_t)tile * (TILE_CELLS * 16);
    #pragma unroll
    for (int k = 0; k < 4; ++k) {
        const int f    = tid + k * 256;   // float4 index within tile (0..1023)
        const int cell = f >> 4;          // 0..63
        const float* sc = s + cell * 17;

        const float x0 = sc[in_off + 0];
        const float x1 = sc[in_off + 1];
        const float x2 = sc[in_off + 2];
        const float x3 = sc[in_off + 3];
        const float x4 = sc[16];          // 5th agent channel (w4==0 for g<3)

        f32x4 e;
        e.x = x0 * w0.x + x1 * w1.x + x2 * w2.x + x3 * w3.x + x4 * w4.x;
        e.y = x0 * w0.y + x1 * w1.y + x2 * w2.y + x3 * w3.y + x4 * w4.y;
        e.z = x0 * w0.z + x1 * w1.z + x2 * w2.z + x3 * w3.z + x4 * w4.z;
        e.w = x0 * w0.w + x1 * w1.w + x2 * w2.w + x3 * w3.w + x4 * w4.w;

        const bool m = csum[cell] > 0.f;
        const int  j = quad * 4;          // output channel of .x
        f32x4 r;
        r.x = m ? e.x : ((j + 0) < 17 ? sc[j + 0] : 0.f);
        r.y = m ? e.y : ((j + 1) < 17 ? sc[j + 1] : 0.f);
        r.z = m ? e.z : ((j + 2) < 17 ? sc[j + 2] : 0.f);
        r.w = m ? e.w : ((j + 3) < 17 ? sc[j + 3] : 0.f);

        // Streaming store: output is never re-read; bypass cache allocation.
        __builtin_nontemporal_store(r, &outv[f]);
    }
}

extern "C" void kernel_launch(void* const* d_in, const int* in_sizes, int n_in,
                              void* d_out, int out_size, void* d_ws, size_t ws_size,
                              hipStream_t stream) {
    const float* sit = (const float*)d_in[0];
    const float* Wsz = (const float*)d_in[1];
    const float* Wsh = (const float*)d_in[2];
    const float* Wrg = (const float*)d_in[3];
    const float* Wag = (const float*)d_in[4];
    float* out = (float*)d_out;

    const int ncells = in_sizes[0] / 17;          // 2048*32*32 = 2,097,152
    const int ntiles = ncells / TILE_CELLS;       // 32768 (exactly divisible)

    gscan_embed_kernel<<<ntiles, 256, 0, stream>>>(sit, Wsz, Wsh, Wrg, Wag, out);
}